// Round 4
// baseline (450.300 us; speedup 1.0000x reference)
//
#include <hip/hip_runtime.h>

#define TDIM 256
#define BM 128
#define BK 32
#define LDST 40   // LDS row stride in bf16 elements (80 B: 16B-aligned, 2-way-max bank aliasing)
#define NSTEP 8

typedef __attribute__((ext_vector_type(4))) float f32x4;
typedef __attribute__((ext_vector_type(8))) short s16x8;
typedef __attribute__((ext_vector_type(8))) __bf16 bf16x8;

// Native __bf16 casts: on gfx950 the compiler lowers f32->bf16 pairs to
// v_cvt_pk_bf16_f32 (learn_hip m240: compiler cast path beats hand-written asm).
__device__ __forceinline__ s16x8 cvt8(f32x4 v0, f32x4 v1) {
    bf16x8 h;
    h[0] = (__bf16)v0[0]; h[1] = (__bf16)v0[1];
    h[2] = (__bf16)v0[2]; h[3] = (__bf16)v0[3];
    h[4] = (__bf16)v1[0]; h[5] = (__bf16)v1[1];
    h[6] = (__bf16)v1[2]; h[7] = (__bf16)v1[3];
    return __builtin_bit_cast(s16x8, h);
}

// Mask (j<=n) then convert: row n of W, columns jbase..jbase+7.
__device__ __forceinline__ s16x8 cvt8_mask(f32x4 v0, f32x4 v1, int jbase, int n) {
    float t[8] = {v0[0], v0[1], v0[2], v0[3], v1[0], v1[1], v1[2], v1[3]};
    bf16x8 h;
#pragma unroll
    for (int e = 0; e < 8; ++e)
        h[e] = (__bf16)((jbase + e) <= n ? t[e] : 0.0f);
    return __builtin_bit_cast(s16x8, h);
}

// X: (M=262144, 256) row-major fp32; W: (256,256) row-major fp32 (row i = weights over j);
// bias: (256,) fp32; out: (M, 256) row-major fp32.
// Block computes BM x 256 output tile. Grid = M/BM = 2048.
__global__ __launch_bounds__(256, 2)
void triu_gemm_kernel(const float* __restrict__ X, const float* __restrict__ W,
                      const float* __restrict__ bias, float* __restrict__ out) {
    __shared__ __align__(16) unsigned short As[2][BM * LDST];   // 2 x 10240 B
    __shared__ __align__(16) unsigned short Bs[2][TDIM * LDST]; // 2 x 20480 B

    const int tid  = threadIdx.x;
    const int wave = tid >> 6;
    const int lane = tid & 63;
    const int quad = lane >> 4;
    const int l16  = lane & 15;
    const int wm   = wave & 1;    // 64-row slice within block tile
    const int wn   = wave >> 1;   // 128-col slice

    const long m0 = (long)blockIdx.x * BM;
    const int rr = tid >> 2;        // 0..63
    const int kq = (tid & 3) * 8;   // 0,8,16,24

    f32x4 acc[4][8];
#pragma unroll
    for (int i = 0; i < 4; ++i)
#pragma unroll
        for (int j = 0; j < 8; ++j)
            acc[i][j] = (f32x4){0.f, 0.f, 0.f, 0.f};

    f32x4 pa[2][2][2];   // X prefetch, depth 2: [slot][row-block][half]
    f32x4 pw[4][2];      // W prefetch, depth 1 (L2-resident)

    // Stage-B with compile-time mask pruning: when the whole row-block sits at or
    // below the diagonal band (p*64 >= kbase+31), no element is masked -> plain cvt.
    // p and kbase are compile-time constants under full unroll, so the branch folds.
#define STAGE_B(buf, p, kbase)                                                     \
    *(s16x8*)&Bs[buf][((p) * 64 + rr) * LDST + kq] =                               \
        (((p) * 64) >= (kbase) + 31)                                               \
            ? cvt8(pw[p][0], pw[p][1])                                             \
            : cvt8_mask(pw[p][0], pw[p][1], (kbase) + kq, (p) * 64 + rr)

    // ---------- prologue ----------
    // Issue order: X tile0, W tile0, X tile1 — staging tile0 waits on W with
    // X tile1 still in flight (vmcnt(4)), keeping the deep prefetch alive.
#pragma unroll
    for (int p = 0; p < 2; ++p) {
        const float* src = X + (m0 + p * 64 + rr) * TDIM + kq;
        pa[0][p][0] = *(const f32x4*)src;
        pa[0][p][1] = *(const f32x4*)(src + 4);
    }
#pragma unroll
    for (int p = 0; p < 4; ++p) {
        const float* src = W + (p * 64 + rr) * TDIM + kq;
        pw[p][0] = *(const f32x4*)src;
        pw[p][1] = *(const f32x4*)(src + 4);
    }
#pragma unroll
    for (int p = 0; p < 2; ++p) {
        const float* src = X + (m0 + p * 64 + rr) * TDIM + BK + kq;
        pa[1][p][0] = *(const f32x4*)src;
        pa[1][p][1] = *(const f32x4*)(src + 4);
    }
#pragma unroll
    for (int p = 0; p < 2; ++p)
        *(s16x8*)&As[0][(p * 64 + rr) * LDST + kq] = cvt8(pa[0][p][0], pa[0][p][1]);
#pragma unroll
    for (int p = 0; p < 4; ++p)
        STAGE_B(0, p, 0);
    __syncthreads();

    // ---------- main loop: double-buffered LDS, X prefetch 2 deep, 1 barrier/K-step ----------
#pragma unroll
    for (int t = 0; t < NSTEP; ++t) {
        const int k0  = t * BK;          // tile being computed (in LDS[cur])
        const int k1  = k0 + BK;         // tile being staged this step (in pa[cur^1]/pw)
        const int k2  = k0 + 2 * BK;     // tile being issued this step (into pa[cur])
        const int cur = t & 1;

        // Issue W tile t+1 FIRST, then X tile t+2: the stage phase's wait for W
        // then leaves the X t+2 loads in flight (compiler emits counted vmcnt).
        if (t < NSTEP - 1) {
#pragma unroll
            for (int p = 0; p < 4; ++p) {
                if (p * 64 + 63 >= k1) {   // row-block entirely masked at k1 -> dead, skip
                    const float* src = W + (p * 64 + rr) * TDIM + (k1 + kq);
                    pw[p][0] = *(const f32x4*)src;
                    pw[p][1] = *(const f32x4*)(src + 4);
                }
            }
        }
        if (t < NSTEP - 2) {
#pragma unroll
            for (int p = 0; p < 2; ++p) {
                const float* src = X + (m0 + p * 64 + rr) * TDIM + (k2 + kq);
                pa[cur][p][0] = *(const f32x4*)src;
                pa[cur][p][1] = *(const f32x4*)(src + 4);
            }
        }

        // Triangle skip: wave's column slice [wn*128, wn*128+128) is dead once k0 >= (wn+1)*128.
        if (k0 < (wn + 1) * 128) {
            s16x8 af[4];
#pragma unroll
            for (int mi = 0; mi < 4; ++mi)
                af[mi] = *(const s16x8*)&As[cur][(wm * 64 + mi * 16 + l16) * LDST + quad * 8];
#pragma unroll
            for (int ni = 0; ni < 8; ++ni) {
                // Fragment rows [f, f+16) all have W==0 when f+15 < k0: exact-zero contribution.
                if (wn * 128 + ni * 16 + 15 >= k0) {
                    const s16x8 bf = *(const s16x8*)&Bs[cur][(wn * 128 + ni * 16 + l16) * LDST + quad * 8];
#pragma unroll
                    for (int mi = 0; mi < 4; ++mi)
                        acc[mi][ni] = __builtin_amdgcn_mfma_f32_16x16x32_bf16(
                            af[mi], bf, acc[mi][ni], 0, 0, 0);
                }
            }
        }

        // Stage tile t+1 (regs -> LDS[cur^1]); single barrier per K-step.
        if (t < NSTEP - 1) {
#pragma unroll
            for (int p = 0; p < 2; ++p)
                *(s16x8*)&As[cur ^ 1][(p * 64 + rr) * LDST + kq] =
                    cvt8(pa[cur ^ 1][p][0], pa[cur ^ 1][p][1]);
#pragma unroll
            for (int p = 0; p < 4; ++p)
                if (p * 64 + 63 >= k1)
                    STAGE_B(cur ^ 1, p, k1);
            __syncthreads();
        }
    }
#undef STAGE_B

    // ---------- epilogue: bias add + store. C/D layout: col = lane&15, row = quad*4 + reg ----------
#pragma unroll
    for (int ni = 0; ni < 8; ++ni) {
        const int n = wn * 128 + ni * 16 + l16;
        const float bv = bias[n];
#pragma unroll
        for (int mi = 0; mi < 4; ++mi) {
            const long mb = m0 + wm * 64 + mi * 16 + quad * 4;
            float* dst = out + mb * TDIM + n;
#pragma unroll
            for (int r = 0; r < 4; ++r)
                dst[(long)r * TDIM] = acc[mi][ni][r] + bv;
        }
    }
}

extern "C" void kernel_launch(void* const* d_in, const int* in_sizes, int n_in,
                              void* d_out, int out_size, void* d_ws, size_t ws_size,
                              hipStream_t stream) {
    const float* X    = (const float*)d_in[0];   // (256,1024,256) = (M=262144, 256)
    const float* W    = (const float*)d_in[1];   // (256,256)
    const float* bias = (const float*)d_in[2];   // (256,)
    float* out        = (float*)d_out;           // (M, 256)
    (void)d_ws; (void)ws_size;

    const int M = 256 * 1024;                    // B*C
    dim3 grid(M / BM);                           // 2048 blocks
    dim3 block(256);
    triu_gemm_kernel<<<grid, block, 0, stream>>>(X, W, bias, out);
}